// Round 3
// baseline (121.273 us; speedup 1.0000x reference)
//
#include <hip/hip_runtime.h>
#include <math.h>

#define BB 256
#define L 512
#define NSIG 50
#define PAD 4
#define STR (L + 2 * PAD)   // 520 floats per padded row

__device__ __forceinline__ int refl(int i) {
    if (i < 0) i = -i;
    if (i >= L) i = 2 * L - 2 - i;
    return i;
}

__device__ __forceinline__ float selu(float x) {
    const float scale = 1.0507009873554804934193349852946f;
    const float alpha = 1.6732632423543772848170429916717f;
    return x > 0.f ? scale * x : scale * alpha * (__expf(x) - 1.f);
}

// ---------------- Kernel A: sharedCNN x2 + residual + LayerNorm ----------------
__global__ __launch_bounds__(256) void shared_ln_kernel(
    const float* __restrict__ latent,   // (B, 2048)
    const float* __restrict__ w1, const float* __restrict__ b1,   // (8,4,5),(8,)
    const float* __restrict__ w2, const float* __restrict__ b2,   // (4,8,5),(4,)
    const float* __restrict__ g,  const float* __restrict__ beta, // (512,),(512,)
    float* __restrict__ D)              // (B,4,512)
{
    __shared__ float xb[4][L];
    __shared__ float hb[8][L];
    __shared__ float yb[4][L];
    __shared__ float sw1[160], sb1[8], sw2[160], sb2[4];

    const int b = blockIdx.x;
    const int t = threadIdx.x;

    for (int i = t; i < 160; i += 256) { sw1[i] = w1[i]; sw2[i] = w2[i]; }
    if (t < 8) sb1[t] = b1[t];
    if (t < 4) sb2[t] = b2[t];

    const float* lp = latent + (size_t)b * 2048;
    for (int i = t; i < 2048; i += 256)
        xb[i & 3][i >> 2] = lp[i];   // x[c][l] = latent[l*4+c]
    __syncthreads();

    for (int pass = 0; pass < 2; ++pass) {
        const float (*src)[L] = (pass == 0) ? (const float (*)[L])xb
                                            : (const float (*)[L])yb;
        // conv1: 4->8, k5, d1, pad2, SELU
        for (int idx = t; idx < 8 * L; idx += 256) {
            int co = idx >> 9, l = idx & (L - 1);
            float acc = sb1[co];
            #pragma unroll
            for (int ci = 0; ci < 4; ++ci) {
                const float* w = &sw1[(co * 4 + ci) * 5];
                #pragma unroll
                for (int k = 0; k < 5; ++k)
                    acc += w[k] * src[ci][refl(l + k - 2)];
            }
            hb[co][l] = selu(acc);
        }
        __syncthreads();
        // conv2: 8->4, k5, d2, pad4 (+ residual on pass 1)
        for (int idx = t; idx < 4 * L; idx += 256) {
            int co = idx >> 9, l = idx & (L - 1);
            float acc = sb2[co];
            #pragma unroll
            for (int ci = 0; ci < 8; ++ci) {
                const float* w = &sw2[(co * 8 + ci) * 5];
                #pragma unroll
                for (int k = 0; k < 5; ++k)
                    acc += w[k] * hb[ci][refl(l + 2 * k - 4)];
            }
            if (pass == 1) acc += xb[co][l];
            yb[co][l] = acc;
        }
        __syncthreads();
    }

    // LayerNorm over length axis, one wave per channel (4 waves = 256 threads)
    const int wave = t >> 6;    // channel 0..3
    const int lane = t & 63;
    float v[8];
    float s = 0.f;
    #pragma unroll
    for (int j = 0; j < 8; ++j) { v[j] = yb[wave][lane * 8 + j]; s += v[j]; }
    #pragma unroll
    for (int off = 32; off > 0; off >>= 1) s += __shfl_down(s, off);
    s = __shfl(s, 0);
    const float mu = s * (1.f / 512.f);
    float s2 = 0.f;
    #pragma unroll
    for (int j = 0; j < 8; ++j) { float d = v[j] - mu; s2 += d * d; }
    #pragma unroll
    for (int off = 32; off > 0; off >>= 1) s2 += __shfl_down(s2, off);
    s2 = __shfl(s2, 0);
    const float rinv = rsqrtf(s2 * (1.f / 512.f) + 1e-10f);

    float* Dp = D + ((size_t)b * 4 + wave) * L;
    #pragma unroll
    for (int j = 0; j < 8; ++j) {
        int l = lane * 8 + j;
        Dp[l] = (v[j] - mu) * rinv * g[l] + beta[l];
    }
}

// ---------------- Kernel B: per-signal channel-reduction stack ----------------
// 128 threads/block, P=4 positions/thread (p0 = 4t). All LDS window loads are
// aligned b64/b128, conflict-free (16B lane stride). Weights via uniform
// s_load. Reflect halo pre-materialized in padded rows -> linear addressing.
// Overlay: bufA = db then h2; bufB = h1 then h3(rows 0..1).
__global__ __launch_bounds__(128) void signal_kernel(
    const float* __restrict__ D,   // (B,4,512)
    const float* __restrict__ w1, const float* __restrict__ b1, // (50,8,4,7),(50,8)
    const float* __restrict__ w2, const float* __restrict__ b2, // (50,4,8,5),(50,4)
    const float* __restrict__ w3, const float* __restrict__ b3, // (50,2,4,5),(50,2)
    const float* __restrict__ w4, const float* __restrict__ b4, // (50,1,2,5),(50,1)
    float* __restrict__ out)       // (B,50,512)
{
    const int s = blockIdx.x;
    const int b = blockIdx.y;
    const int t = threadIdx.x;     // 0..127
    const int p0 = t * 4;          // this thread's four positions

    __shared__ float bufA[4][STR]; // db, then h2
    __shared__ float bufB[8][STR]; // h1, then h3 (rows 0..1)

    const float* W1 = w1 + s * 224; const float* B1 = b1 + s * 8;
    const float* W2 = w2 + s * 160; const float* B2 = b2 + s * 4;
    const float* W3 = w3 + s * 40;  const float* B3 = b3 + s * 2;
    const float* W4 = w4 + s * 10;

    // ---- load D into bufA interior (float4 global + b128 LDS writes) ----
    {
        const float4* Dv = (const float4*)(D + (size_t)b * 2048);
        #pragma unroll
        for (int j = 0; j < 4; ++j) {
            int i = t + j * 128;               // float4 index 0..511
            float4 v = Dv[i];
            int c = i >> 7, col = (i & 127) << 2;
            *(float4*)&bufA[c][PAD + col] = v;
        }
    }
    __syncthreads();
    if (t < 32) {    // halo A (4 rows x 8)
        int r = t >> 3, j = t & 7;
        if (j < 4) bufA[r][PAD - 1 - j] = bufA[r][PAD + 1 + j];
        else { int i = j - 4; bufA[r][PAD + L + i] = bufA[r][PAD + L - 2 - i]; }
    }
    __syncthreads();

    // ---- conv1: 4->8, k7, pad3. reads bufA, writes bufB ----
    {
        float acc[8][4];
        #pragma unroll
        for (int co = 0; co < 8; ++co) {
            float bb = B1[co];
            #pragma unroll
            for (int pp = 0; pp < 4; ++pp) acc[co][pp] = bb;
        }
        #pragma unroll
        for (int ci = 0; ci < 4; ++ci) {
            float x[12];                        // positions p0-4 .. p0+7
            const float* row = &bufA[ci][p0];   // element index PAD+p0-4
            *(float4*)&x[0] = *(const float4*)&row[0];
            *(float4*)&x[4] = *(const float4*)&row[4];
            *(float4*)&x[8] = *(const float4*)&row[8];
            #pragma unroll
            for (int co = 0; co < 8; ++co)
                #pragma unroll
                for (int k = 0; k < 7; ++k) {
                    float w = W1[(co * 4 + ci) * 7 + k];
                    #pragma unroll
                    for (int pp = 0; pp < 4; ++pp)
                        acc[co][pp] += w * x[pp + k + 1];
                }
        }
        #pragma unroll
        for (int co = 0; co < 8; ++co) {
            float4 v = { acc[co][0], acc[co][1], acc[co][2], acc[co][3] };
            *(float4*)&bufB[co][PAD + p0] = v;
        }
    }
    __syncthreads();
    if (t < 64) {    // halo B (8 rows x 8)
        int r = t >> 3, j = t & 7;
        if (j < 4) bufB[r][PAD - 1 - j] = bufB[r][PAD + 1 + j];
        else { int i = j - 4; bufB[r][PAD + L + i] = bufB[r][PAD + L - 2 - i]; }
    }
    __syncthreads();

    // ---- conv2: 8->4, k5, pad2, SELU. reads bufB, writes bufA ----
    {
        float acc[4][4];
        #pragma unroll
        for (int co = 0; co < 4; ++co) {
            float bb = B2[co];
            #pragma unroll
            for (int pp = 0; pp < 4; ++pp) acc[co][pp] = bb;
        }
        #pragma unroll
        for (int ci = 0; ci < 8; ++ci) {
            float x[8];                             // positions p0-2 .. p0+5
            const float* row = &bufB[ci][p0 + 2];   // element index PAD+p0-2
            *(float2*)&x[0] = *(const float2*)&row[0];
            *(float4*)&x[2] = *(const float4*)&row[2];
            *(float2*)&x[6] = *(const float2*)&row[6];
            #pragma unroll
            for (int co = 0; co < 4; ++co)
                #pragma unroll
                for (int k = 0; k < 5; ++k) {
                    float w = W2[(co * 8 + ci) * 5 + k];
                    #pragma unroll
                    for (int pp = 0; pp < 4; ++pp)
                        acc[co][pp] += w * x[pp + k];
                }
        }
        #pragma unroll
        for (int co = 0; co < 4; ++co) {
            float4 v = { selu(acc[co][0]), selu(acc[co][1]),
                         selu(acc[co][2]), selu(acc[co][3]) };
            *(float4*)&bufA[co][PAD + p0] = v;
        }
    }
    __syncthreads();
    if (t < 32) {    // halo A (4 rows x 8)
        int r = t >> 3, j = t & 7;
        if (j < 4) bufA[r][PAD - 1 - j] = bufA[r][PAD + 1 + j];
        else { int i = j - 4; bufA[r][PAD + L + i] = bufA[r][PAD + L - 2 - i]; }
    }
    __syncthreads();

    // ---- conv3: 4->2, k5, pad2. reads bufA, writes bufB rows 0..1 ----
    {
        float acc[2][4];
        #pragma unroll
        for (int co = 0; co < 2; ++co) {
            float bb = B3[co];
            #pragma unroll
            for (int pp = 0; pp < 4; ++pp) acc[co][pp] = bb;
        }
        #pragma unroll
        for (int ci = 0; ci < 4; ++ci) {
            float x[8];
            const float* row = &bufA[ci][p0 + 2];
            *(float2*)&x[0] = *(const float2*)&row[0];
            *(float4*)&x[2] = *(const float4*)&row[2];
            *(float2*)&x[6] = *(const float2*)&row[6];
            #pragma unroll
            for (int co = 0; co < 2; ++co)
                #pragma unroll
                for (int k = 0; k < 5; ++k) {
                    float w = W3[(co * 4 + ci) * 5 + k];
                    #pragma unroll
                    for (int pp = 0; pp < 4; ++pp)
                        acc[co][pp] += w * x[pp + k];
                }
        }
        #pragma unroll
        for (int co = 0; co < 2; ++co) {
            float4 v = { acc[co][0], acc[co][1], acc[co][2], acc[co][3] };
            *(float4*)&bufB[co][PAD + p0] = v;
        }
    }
    __syncthreads();
    if (t < 16) {    // halo B rows 0..1
        int r = t >> 3, j = t & 7;
        if (j < 4) bufB[r][PAD - 1 - j] = bufB[r][PAD + 1 + j];
        else { int i = j - 4; bufB[r][PAD + L + i] = bufB[r][PAD + L - 2 - i]; }
    }
    __syncthreads();

    // ---- conv4: 2->1, k5, d2, pad4, SELU. reads bufB rows 0..1 -> out ----
    {
        float acc[4];
        float bb = b4[s];
        #pragma unroll
        for (int pp = 0; pp < 4; ++pp) acc[pp] = bb;
        #pragma unroll
        for (int ci = 0; ci < 2; ++ci) {
            float x[12];                        // positions p0-4 .. p0+7
            const float* row = &bufB[ci][p0];
            *(float4*)&x[0] = *(const float4*)&row[0];
            *(float4*)&x[4] = *(const float4*)&row[4];
            *(float4*)&x[8] = *(const float4*)&row[8];
            #pragma unroll
            for (int k = 0; k < 5; ++k) {
                float w = W4[ci * 5 + k];
                #pragma unroll
                for (int pp = 0; pp < 4; ++pp)
                    acc[pp] += w * x[pp + 2 * k];
            }
        }
        float4 r = { selu(acc[0]), selu(acc[1]), selu(acc[2]), selu(acc[3]) };
        *(float4*)&out[((size_t)b * NSIG + s) * L + p0] = r;
    }
}

extern "C" void kernel_launch(void* const* d_in, const int* in_sizes, int n_in,
                              void* d_out, int out_size, void* d_ws, size_t ws_size,
                              hipStream_t stream) {
    const float* latent = (const float*)d_in[0];
    const float* sw1 = (const float*)d_in[1];
    const float* sb1 = (const float*)d_in[2];
    const float* sw2 = (const float*)d_in[3];
    const float* sb2 = (const float*)d_in[4];
    const float* ln_g = (const float*)d_in[5];
    const float* ln_b = (const float*)d_in[6];
    const float* g_w1 = (const float*)d_in[7];
    const float* g_b1 = (const float*)d_in[8];
    const float* g_w2 = (const float*)d_in[9];
    const float* g_b2 = (const float*)d_in[10];
    const float* g_w3 = (const float*)d_in[11];
    const float* g_b3 = (const float*)d_in[12];
    const float* g_w4 = (const float*)d_in[13];
    const float* g_b4 = (const float*)d_in[14];
    float* out = (float*)d_out;
    float* D = (float*)d_ws;   // (256,4,512) f32 = 2 MB

    shared_ln_kernel<<<BB, 256, 0, stream>>>(latent, sw1, sb1, sw2, sb2,
                                             ln_g, ln_b, D);
    signal_kernel<<<dim3(NSIG, BB), 128, 0, stream>>>(D, g_w1, g_b1, g_w2, g_b2,
                                                      g_w3, g_b3, g_w4, g_b4, out);
}